// Round 4
// baseline (767.859 us; speedup 1.0000x reference)
//
#include <hip/hip_runtime.h>
#include <math.h>

// FactorizationMachine: out = sigmoid( X@fc_w + fc_b + 0.5*( sum_d (X@w)_d^2 - (X^2)@g ) )
// with g[f] = sum_d w[f,d]^2 computed inline.
//
// R3: R0 ran at 6.4 TB/s aggregate (peak) but moved ~1.9 GB: X 819 MB + ~1.1 GB
// of W re-fetches (512 blocks x 3.2 MB logical) escaping the 4 MiB/XCD L2s.
// R2's restructure regressed for schedule reasons (W loads serialized in j-loop).
// So: keep R0's EXACT inner loop (thread-stride-256, hoisted W loads), add
// K-split x8 with chunk = blockIdx & 7 -> each XCD's L2 only holds its 400 KB
// W chunk (10% of L2; ~32 co-resident blocks/XCD share it). Partials to d_ws,
// tiny phase-2 reduces 8 chunks/row + epilogue.

constexpr int B_ROWS   = 4096;
constexpr int F_FEAT   = 50000;
constexpr int NF4      = F_FEAT / 4;        // 12500
constexpr int D_FAC    = 16;
constexpr int ROWS     = 8;                 // rows per block
constexpr int THREADS  = 256;
constexpr int KSPLIT   = 8;
constexpr int CHUNK_F4 = (NF4 + KSPLIT - 1) / KSPLIT;  // 1563
constexpr int NGROUP   = B_ROWS / ROWS;     // 512 row-groups
constexpr int NVAL     = ROWS * (D_FAC + 1);            // 136 partials per block

typedef float f32x4 __attribute__((ext_vector_type(4)));

__device__ __forceinline__ f32x4 ntload4(const f32x4* p) {
    return __builtin_nontemporal_load(p);
}

__global__ __launch_bounds__(THREADS)
void fm_phase1(const float* __restrict__ X,
               const float* __restrict__ fcw,
               const float* __restrict__ W,
               float* __restrict__ ws)
{
    const int tid  = threadIdx.x;
    const int c    = blockIdx.x & (KSPLIT - 1);   // F-chunk; %8 dispatch -> one XCD
    const int g    = blockIdx.x >> 3;             // row-group
    const int row0 = g * ROWS;
    const int f4_beg = c * CHUNK_F4;
    const int f4_end = min(NF4, f4_beg + CHUNK_F4);

    const f32x4* X4  = reinterpret_cast<const f32x4*>(X);
    const f32x4* W4  = reinterpret_cast<const f32x4*>(W);
    const f32x4* FW4 = reinterpret_cast<const f32x4*>(fcw);

    float s[ROWS][D_FAC];
    float lin[ROWS];
#pragma unroll
    for (int r = 0; r < ROWS; ++r) {
        lin[r] = 0.f;
#pragma unroll
        for (int d = 0; d < D_FAC; ++d) s[r][d] = 0.f;
    }

    for (int f4 = f4_beg + tid; f4 < f4_end; f4 += THREADS) {
        // X: 8 independent coalesced streams (one per row), non-temporal (no reuse)
        f32x4 xv[ROWS];
#pragma unroll
        for (int r = 0; r < ROWS; ++r)
            xv[r] = ntload4(&X4[(size_t)(row0 + r) * NF4 + f4]);

        // w rows for 4 consecutive features, HOISTED up front (R0 schedule):
        // 256 contiguous bytes per lane, L2-resident (chunk pinned to this XCD)
        f32x4 wv[16];
#pragma unroll
        for (int q = 0; q < 16; ++q)
            wv[q] = W4[(size_t)f4 * 16 + q];

        const f32x4 fw = FW4[f4];

#pragma unroll
        for (int j = 0; j < 4; ++j) {          // 4 features in this float4 group
            float wd[D_FAC];
#pragma unroll
            for (int t = 0; t < D_FAC; ++t)
                wd[t] = wv[4 * j + (t >> 2)][t & 3];

            // g' = -0.5 * sum_d w_d^2  (amortized over 8 rows)
            float gp = 0.f;
#pragma unroll
            for (int t = 0; t < D_FAC; ++t) gp = fmaf(wd[t], wd[t], gp);
            gp *= -0.5f;

            const float fwj = fw[j];
#pragma unroll
            for (int r = 0; r < ROWS; ++r) {
                const float x  = xv[r][j];
                const float x2 = x * x;
                lin[r] = fmaf(x, fwj, lin[r]);
                lin[r] = fmaf(x2, gp, lin[r]);
#pragma unroll
                for (int t = 0; t < D_FAC; ++t)
                    s[r][t] = fmaf(x, wd[t], s[r][t]);
            }
        }
    }

    // ---- reduction: 64-lane butterfly, then cross-wave via LDS (R0 epilogue) ----
    __shared__ float part[THREADS / 64][NVAL];
    const int lane = tid & 63;
    const int wid  = tid >> 6;

#pragma unroll
    for (int r = 0; r < ROWS; ++r) {
#pragma unroll
        for (int t = 0; t < D_FAC; ++t) {
            float v = s[r][t];
#pragma unroll
            for (int m = 32; m >= 1; m >>= 1) v += __shfl_xor(v, m, 64);
            if (lane == 0) part[wid][r * 17 + t] = v;
        }
        float v = lin[r];
#pragma unroll
        for (int m = 32; m >= 1; m >>= 1) v += __shfl_xor(v, m, 64);
        if (lane == 0) part[wid][r * 17 + 16] = v;
    }
    __syncthreads();

    // 136 partials -> ws[blockIdx][136], coalesced
    if (tid < NVAL) {
        ws[(size_t)blockIdx.x * NVAL + tid] =
            part[0][tid] + part[1][tid] + part[2][tid] + part[3][tid];
    }
}

__global__ __launch_bounds__(256)
void fm_phase2(const float* __restrict__ ws,
               const float* __restrict__ fcb,
               float* __restrict__ out)
{
    const int r = blockIdx.x * 256 + threadIdx.x;
    if (r >= B_ROWS) return;
    const int g  = r >> 3;          // row-group
    const int rr = r & 7;           // row within group

    float acc[D_FAC + 1];
#pragma unroll
    for (int t = 0; t <= D_FAC; ++t) acc[t] = 0.f;

    for (int c = 0; c < KSPLIT; ++c) {
        const float* base = ws + ((size_t)(g * KSPLIT + c)) * NVAL + rr * (D_FAC + 1);
#pragma unroll
        for (int t = 0; t <= D_FAC; ++t) acc[t] += base[t];
    }

    float ss = 0.f;
#pragma unroll
    for (int t = 0; t < D_FAC; ++t) ss = fmaf(acc[t], acc[t], ss);

    const float logit = acc[D_FAC] + fcb[0] + 0.5f * ss;
    out[r] = 1.0f / (1.0f + expf(-logit));
}

extern "C" void kernel_launch(void* const* d_in, const int* in_sizes, int n_in,
                              void* d_out, int out_size, void* d_ws, size_t ws_size,
                              hipStream_t stream)
{
    const float* X   = (const float*)d_in[0];
    const float* fcw = (const float*)d_in[1];
    const float* fcb = (const float*)d_in[2];
    const float* W   = (const float*)d_in[3];
    float* out = (float*)d_out;
    float* ws  = (float*)d_ws;   // needs 4096*136*4 B = 2.23 MB

    dim3 grid1(NGROUP * KSPLIT);     // 4096 blocks; chunk = blockIdx & 7 -> XCD
    hipLaunchKernelGGL(fm_phase1, grid1, dim3(THREADS), 0, stream, X, fcw, W, ws);

    dim3 grid2((B_ROWS + 255) / 256);
    hipLaunchKernelGGL(fm_phase2, grid2, dim3(256), 0, stream, ws, fcb, out);
}

// Round 5
// 289.002 us; speedup vs baseline: 2.6569x; 2.6569x over previous
//
#include <hip/hip_runtime.h>
#include <math.h>

// FactorizationMachine: out = sigmoid( X@fc_w + fc_b + 0.5*( sum_d (X@w)_d^2 - (X^2)@g ) )
// with g[f] = sum_d w[f,d]^2 computed inline.
//
// R4: R3's counters showed OccupancyPercent=12% == 1 wave/SIMD. Cause: 136
// accumulators + 32 xv + 64 wv + addr ≈ 268 regs/wave in the unified VGPR/AGPR
// file > 256 -> single-wave occupancy -> zero latency hiding (VALUBusy 13%,
// HBM 541 GB/s, nothing near roofline). All prior byte-centric theories were
// wrong; dur tracked iterations-per-wave (pipeline-fill at occupancy 1).
//
// Fix: exact R0 structure (512 blocks, full-F sweep, 49 iter/wave, single
// kernel) but W loaded in TWO batches of 8 f32x4 reusing the same registers
// (j=0,1 then j=2,3): same load count/bytes, -32 live VGPRs -> ~236/wave.
// __launch_bounds__(256,2) forces the allocator to fit 2 waves/EU.

constexpr int B_ROWS  = 4096;
constexpr int F_FEAT  = 50000;
constexpr int NF4     = F_FEAT / 4;   // 12500 float4 groups per row
constexpr int D_FAC   = 16;
constexpr int ROWS    = 8;            // rows per block (amortizes w loads 8x)
constexpr int THREADS = 256;
constexpr int NVAL    = ROWS * (D_FAC + 1); // 136 partial values per block

typedef float f32x4 __attribute__((ext_vector_type(4)));

__device__ __forceinline__ f32x4 ntload4(const f32x4* p) {
    return __builtin_nontemporal_load(p);
}

__global__ __launch_bounds__(THREADS, 2)   // min 2 waves/EU: combined regs <= 256
void fm_onehot_kernel(const float* __restrict__ X,
                      const float* __restrict__ fcw,
                      const float* __restrict__ fcb,
                      const float* __restrict__ W,
                      float* __restrict__ out)
{
    const int tid  = threadIdx.x;
    const int row0 = blockIdx.x * ROWS;

    const f32x4* X4  = reinterpret_cast<const f32x4*>(X);
    const f32x4* W4  = reinterpret_cast<const f32x4*>(W);
    const f32x4* FW4 = reinterpret_cast<const f32x4*>(fcw);

    float s[ROWS][D_FAC];
    float lin[ROWS];
#pragma unroll
    for (int r = 0; r < ROWS; ++r) {
        lin[r] = 0.f;
#pragma unroll
        for (int d = 0; d < D_FAC; ++d) s[r][d] = 0.f;
    }

    for (int f4 = tid; f4 < NF4; f4 += THREADS) {
        // X: 8 independent coalesced streams (one per row), non-temporal
        f32x4 xv[ROWS];
#pragma unroll
        for (int r = 0; r < ROWS; ++r)
            xv[r] = ntload4(&X4[(size_t)(row0 + r) * NF4 + f4]);

        const f32x4 fw = FW4[f4];

        // W batch 1: rows for features j=0,1 (8 f32x4, reused registers)
        f32x4 wv[8];
#pragma unroll
        for (int q = 0; q < 8; ++q)
            wv[q] = W4[(size_t)f4 * 16 + q];

#pragma unroll
        for (int j = 0; j < 2; ++j) {
            float wd[D_FAC];
#pragma unroll
            for (int t = 0; t < D_FAC; ++t)
                wd[t] = wv[4 * j + (t >> 2)][t & 3];

            float gp = 0.f;
#pragma unroll
            for (int t = 0; t < D_FAC; ++t) gp = fmaf(wd[t], wd[t], gp);
            gp *= -0.5f;

            const float fwj = fw[j];
#pragma unroll
            for (int r = 0; r < ROWS; ++r) {
                const float x  = xv[r][j];
                const float x2 = x * x;
                lin[r] = fmaf(x, fwj, lin[r]);
                lin[r] = fmaf(x2, gp, lin[r]);
#pragma unroll
                for (int t = 0; t < D_FAC; ++t)
                    s[r][t] = fmaf(x, wd[t], s[r][t]);
            }
        }

        // W batch 2: rows for features j=2,3 (same 8 registers)
#pragma unroll
        for (int q = 0; q < 8; ++q)
            wv[q] = W4[(size_t)f4 * 16 + 8 + q];

#pragma unroll
        for (int j = 0; j < 2; ++j) {
            const int jj = j + 2;
            float wd[D_FAC];
#pragma unroll
            for (int t = 0; t < D_FAC; ++t)
                wd[t] = wv[4 * j + (t >> 2)][t & 3];

            float gp = 0.f;
#pragma unroll
            for (int t = 0; t < D_FAC; ++t) gp = fmaf(wd[t], wd[t], gp);
            gp *= -0.5f;

            const float fwj = fw[jj];
#pragma unroll
            for (int r = 0; r < ROWS; ++r) {
                const float x  = xv[r][jj];
                const float x2 = x * x;
                lin[r] = fmaf(x, fwj, lin[r]);
                lin[r] = fmaf(x2, gp, lin[r]);
#pragma unroll
                for (int t = 0; t < D_FAC; ++t)
                    s[r][t] = fmaf(x, wd[t], s[r][t]);
            }
        }
    }

    // ---- reduction: 64-lane butterfly, then cross-wave via LDS ----
    __shared__ float part[THREADS / 64][NVAL];
    __shared__ float red[NVAL];
    const int lane = tid & 63;
    const int wid  = tid >> 6;

#pragma unroll
    for (int r = 0; r < ROWS; ++r) {
#pragma unroll
        for (int t = 0; t < D_FAC; ++t) {
            float v = s[r][t];
#pragma unroll
            for (int m = 32; m >= 1; m >>= 1) v += __shfl_xor(v, m, 64);
            if (lane == 0) part[wid][r * 17 + t] = v;
        }
        float v = lin[r];
#pragma unroll
        for (int m = 32; m >= 1; m >>= 1) v += __shfl_xor(v, m, 64);
        if (lane == 0) part[wid][r * 17 + 16] = v;
    }
    __syncthreads();

    if (tid < NVAL) {
        red[tid] = part[0][tid] + part[1][tid] + part[2][tid] + part[3][tid];
    }
    __syncthreads();

    if (tid < ROWS) {
        float acc = red[tid * 17 + 16] + fcb[0];
        float ss  = 0.f;
#pragma unroll
        for (int t = 0; t < D_FAC; ++t) {
            const float sv = red[tid * 17 + t];
            ss = fmaf(sv, sv, ss);
        }
        const float logit = acc + 0.5f * ss;
        out[row0 + tid] = 1.0f / (1.0f + expf(-logit));
    }
}

extern "C" void kernel_launch(void* const* d_in, const int* in_sizes, int n_in,
                              void* d_out, int out_size, void* d_ws, size_t ws_size,
                              hipStream_t stream)
{
    const float* X   = (const float*)d_in[0];
    const float* fcw = (const float*)d_in[1];
    const float* fcb = (const float*)d_in[2];
    const float* W   = (const float*)d_in[3];
    float* out = (float*)d_out;

    dim3 grid(B_ROWS / ROWS);   // 512 blocks
    dim3 block(THREADS);
    hipLaunchKernelGGL(fm_onehot_kernel, grid, block, 0, stream,
                       X, fcw, fcb, W, out);
}